// Round 2
// baseline (860.545 us; speedup 1.0000x reference)
//
#include <hip/hip_runtime.h>
#include <hip/hip_bf16.h>

typedef __attribute__((ext_vector_type(8))) short short8;
typedef __attribute__((ext_vector_type(4))) float f32x4;

#define SEQ 8192
#define NBATCH 4

static __device__ __forceinline__ unsigned short f2bf(float f) {
    __hip_bfloat16 h = __float2bfloat16(f);
    unsigned short u;
    __builtin_memcpy(&u, &h, 2);
    return u;
}

static __device__ __forceinline__ int4 pack8(float4 a, float4 b) {
    union { unsigned short s[8]; int4 i; } r;
    r.s[0] = f2bf(a.x); r.s[1] = f2bf(a.y); r.s[2] = f2bf(a.z); r.s[3] = f2bf(a.w);
    r.s[4] = f2bf(b.x); r.s[5] = f2bf(b.y); r.s[6] = f2bf(b.z); r.s[7] = f2bf(b.w);
    return r.i;
}

// C[M][N] = A[M][256] * W[N][256]^T (+bias)*scale.  Tile 128x128, 4 waves,
// each wave 64x64 as 4x4 frags of 16x16x32 bf16 MFMA.
// LDS rows padded +8 bf16 (80B stride) -> b128 frag reads land 8 lanes per
// 16B slot = conflict floor.
template<bool A_BF16, bool OUT_F32>
__global__ __launch_bounds__(256) void proj_gemm(
    const void* __restrict__ Ap, const float* __restrict__ W,
    const float* __restrict__ bias, void* __restrict__ Outp, float scale)
{
    __shared__ alignas(16) unsigned short As[128][40];
    __shared__ alignas(16) unsigned short Bs[128][40];

    const int tid  = threadIdx.x;
    const int lane = tid & 63;
    const int wv   = tid >> 6;
    const int wm   = (wv >> 1) * 64, wn = (wv & 1) * 64;
    const int lr   = lane & 15, lg = lane >> 4;
    const int m0   = blockIdx.x * 128;
    const int n0   = blockIdx.y * 128;

    const int srow = tid >> 1;          // 0..127
    const int skc  = (tid & 1) * 16;    // 0 or 16

    f32x4 acc[4][4] = {};

    for (int k0 = 0; k0 < 256; k0 += 32) {
        __syncthreads();
        // stage A tile [128][32]
        if (A_BF16) {
            const unsigned short* a = (const unsigned short*)Ap + (size_t)(m0 + srow) * 256 + k0 + skc;
            int4 v0 = *(const int4*)a;
            int4 v1 = *(const int4*)(a + 8);
            *(int4*)&As[srow][skc]     = v0;
            *(int4*)&As[srow][skc + 8] = v1;
        } else {
            const float* a = (const float*)Ap + (size_t)(m0 + srow) * 256 + k0 + skc;
            const float4* a4 = (const float4*)a;
            *(int4*)&As[srow][skc]     = pack8(a4[0], a4[1]);
            *(int4*)&As[srow][skc + 8] = pack8(a4[2], a4[3]);
        }
        // stage B tile [128][32] from W (fp32, rows = output cols)
        {
            const float* b = W + (size_t)(n0 + srow) * 256 + k0 + skc;
            const float4* b4 = (const float4*)b;
            *(int4*)&Bs[srow][skc]     = pack8(b4[0], b4[1]);
            *(int4*)&Bs[srow][skc + 8] = pack8(b4[2], b4[3]);
        }
        __syncthreads();

        short8 af[4], bfr[4];
        #pragma unroll
        for (int fm = 0; fm < 4; ++fm)
            af[fm] = *(const short8*)&As[wm + fm * 16 + lr][lg * 8];
        #pragma unroll
        for (int fn = 0; fn < 4; ++fn)
            bfr[fn] = *(const short8*)&Bs[wn + fn * 16 + lr][lg * 8];
        #pragma unroll
        for (int fm = 0; fm < 4; ++fm)
            #pragma unroll
            for (int fn = 0; fn < 4; ++fn)
                acc[fm][fn] = __builtin_amdgcn_mfma_f32_16x16x32_bf16(
                    af[fm], bfr[fn], acc[fm][fn], 0, 0, 0);
    }

    float bvals[4];
    #pragma unroll
    for (int fn = 0; fn < 4; ++fn) bvals[fn] = bias[n0 + wn + fn * 16 + lr];

    #pragma unroll
    for (int fm = 0; fm < 4; ++fm) {
        #pragma unroll
        for (int fn = 0; fn < 4; ++fn) {
            #pragma unroll
            for (int r = 0; r < 4; ++r) {
                const int row = m0 + wm + fm * 16 + lg * 4 + r;
                const int col = n0 + wn + fn * 16 + lr;
                float val = (acc[fm][fn][r] + bvals[fn]) * scale;
                if (OUT_F32) ((float*)Outp)[(size_t)row * 256 + col] = val;
                else ((unsigned short*)Outp)[(size_t)row * 256 + col] = f2bf(val);
            }
        }
    }
}

// Flash attention. Q pre-scaled by 1/sqrt(d). 4 waves x 16 q-rows, KVBLK=32.
// Scores D-layout: row q = lg*4+r, col kv = tile*16+lr. Softmax row-reduce via
// shfl_xor over the 16-lane group. P goes through per-wave LDS (wave-local,
// in-order LDS => no barrier) to reach the A-operand layout. V transposed into
// LDS at stage time so PV B-frags are contiguous b128 reads.
__global__ __launch_bounds__(256) void attn_kernel(
    const unsigned short* __restrict__ Q, const unsigned short* __restrict__ K,
    const unsigned short* __restrict__ V, unsigned short* __restrict__ A)
{
    __shared__ alignas(16) unsigned short Ks[32][264];   // [kv][d], pad +8
    __shared__ alignas(16) unsigned short Vt[256][40];   // [d][kv], pad +8
    __shared__ alignas(16) unsigned short Ps[4][16][40]; // per-wave [q][kv], pad +8

    const int tid  = threadIdx.x;
    const int lane = tid & 63;
    const int wv   = tid >> 6;
    const int lr   = lane & 15, lg = lane >> 4;
    const int b    = blockIdx.y;
    const size_t qbase = (size_t)b * SEQ + blockIdx.x * 64 + wv * 16;

    short8 aq[8];
    #pragma unroll
    for (int c = 0; c < 8; ++c)
        aq[c] = *(const short8*)&Q[(qbase + lr) * 256 + c * 32 + lg * 8];

    float m_run[4], l_run[4];
    f32x4 o[16] = {};
    #pragma unroll
    for (int r = 0; r < 4; ++r) { m_run[r] = -1e30f; l_run[r] = 0.f; }

    const int krow = tid >> 3, kcol = (tid & 7) * 32;   // K staging map
    const int vrow = tid & 31, vc   = (tid >> 5) * 32;  // V staging map

    for (int it = 0; it < SEQ / 32; ++it) {
        const size_t kv0 = (size_t)b * SEQ + (size_t)it * 32;
        __syncthreads();
        {   // stage K tile [32][256] row-major
            const int4* src = (const int4*)&K[(kv0 + krow) * 256 + kcol];
            int4 x0 = src[0], x1 = src[1], x2 = src[2], x3 = src[3];
            *(int4*)&Ks[krow][kcol]      = x0;
            *(int4*)&Ks[krow][kcol + 8]  = x1;
            *(int4*)&Ks[krow][kcol + 16] = x2;
            *(int4*)&Ks[krow][kcol + 24] = x3;
        }
        {   // stage V tile transposed -> Vt[d][kv]
            const int4* src = (const int4*)&V[(kv0 + vrow) * 256 + vc];
            int4 y[4];
            y[0] = src[0]; y[1] = src[1]; y[2] = src[2]; y[3] = src[3];
            const unsigned short* ys = (const unsigned short*)y;
            #pragma unroll
            for (int j = 0; j < 32; ++j) Vt[vc + j][vrow] = ys[j];
        }
        __syncthreads();

        // QK^T: two 16x16 col-tiles over kv, K=256 in 8 chunks
        f32x4 s0 = {}, s1 = {};
        #pragma unroll
        for (int c = 0; c < 8; ++c) {
            short8 kb0 = *(const short8*)&Ks[lr][c * 32 + lg * 8];
            short8 kb1 = *(const short8*)&Ks[16 + lr][c * 32 + lg * 8];
            s0 = __builtin_amdgcn_mfma_f32_16x16x32_bf16(aq[c], kb0, s0, 0, 0, 0);
            s1 = __builtin_amdgcn_mfma_f32_16x16x32_bf16(aq[c], kb1, s1, 0, 0, 0);
        }

        // online softmax per q-row (row = lg*4+r)
        #pragma unroll
        for (int r = 0; r < 4; ++r) {
            float mx = fmaxf(s0[r], s1[r]);
            #pragma unroll
            for (int sh = 1; sh < 16; sh <<= 1) mx = fmaxf(mx, __shfl_xor(mx, sh, 64));
            float mnew = fmaxf(m_run[r], mx);
            float corr = __expf(m_run[r] - mnew);
            float p0 = __expf(s0[r] - mnew);
            float p1 = __expf(s1[r] - mnew);
            float rs = p0 + p1;
            #pragma unroll
            for (int sh = 1; sh < 16; sh <<= 1) rs += __shfl_xor(rs, sh, 64);
            l_run[r] = l_run[r] * corr + rs;
            m_run[r] = mnew;
            #pragma unroll
            for (int nt = 0; nt < 16; ++nt) o[nt][r] *= corr;
            Ps[wv][lg * 4 + r][lr]      = f2bf(p0);
            Ps[wv][lg * 4 + r][16 + lr] = f2bf(p1);
        }

        // P -> A-operand frag (wave-local LDS roundtrip, no barrier needed)
        short8 pa = *(const short8*)&Ps[wv][lr][lg * 8];

        // PV: O[16 q][256 d] += P[16][32] * V[32][256]
        #pragma unroll
        for (int nt = 0; nt < 16; ++nt) {
            short8 vb = *(const short8*)&Vt[nt * 16 + lr][lg * 8];
            o[nt] = __builtin_amdgcn_mfma_f32_16x16x32_bf16(pa, vb, o[nt], 0, 0, 0);
        }
    }

    float inv[4];
    #pragma unroll
    for (int r = 0; r < 4; ++r) inv[r] = 1.f / l_run[r];
    #pragma unroll
    for (int nt = 0; nt < 16; ++nt)
        #pragma unroll
        for (int r = 0; r < 4; ++r)
            A[(qbase + lg * 4 + r) * 256 + nt * 16 + lr] = f2bf(o[nt][r] * inv[r]);
}

extern "C" void kernel_launch(void* const* d_in, const int* in_sizes, int n_in,
                              void* d_out, int out_size, void* d_ws, size_t ws_size,
                              hipStream_t stream) {
    (void)in_sizes; (void)n_in; (void)out_size; (void)ws_size;
    const float* x  = (const float*)d_in[0];
    const float* Wq = (const float*)d_in[1];
    const float* bq = (const float*)d_in[2];
    const float* Wk = (const float*)d_in[3];
    const float* bk = (const float*)d_in[4];
    const float* Wv = (const float*)d_in[5];
    const float* bv = (const float*)d_in[6];
    const float* Wo = (const float*)d_in[7];
    const float* bo = (const float*)d_in[8];
    float* out = (float*)d_out;

    char* ws = (char*)d_ws;
    const size_t MB16 = (size_t)16 * 1024 * 1024;
    unsigned short* qb = (unsigned short*)(ws);
    unsigned short* kb = (unsigned short*)(ws + MB16);
    unsigned short* vb = (unsigned short*)(ws + 2 * MB16);
    unsigned short* ab = (unsigned short*)(ws + 3 * MB16);

    dim3 gg(256, 2), bb(256);
    // q = (x Wq^T + bq) * d^-0.5  (scale folded into Q)
    proj_gemm<false, false><<<gg, bb, 0, stream>>>(x, Wq, bq, qb, 0.0625f);
    proj_gemm<false, false><<<gg, bb, 0, stream>>>(x, Wk, bk, kb, 1.0f);
    proj_gemm<false, false><<<gg, bb, 0, stream>>>(x, Wv, bv, vb, 1.0f);
    attn_kernel<<<dim3(128, NBATCH), bb, 0, stream>>>(qb, kb, vb, ab);
    proj_gemm<true, true><<<gg, bb, 0, stream>>>(ab, Wo, bo, out, 1.0f);
}

// Round 4
// 745.008 us; speedup vs baseline: 1.1551x; 1.1551x over previous
//
#include <hip/hip_runtime.h>
#include <hip/hip_bf16.h>

typedef __attribute__((ext_vector_type(8))) short short8;
typedef __attribute__((ext_vector_type(4))) float f32x4;

#define SEQ 8192
#define NBATCH 4

static __device__ __forceinline__ unsigned short f2bf(float f) {
    __hip_bfloat16 h = __float2bfloat16(f);
    unsigned short u;
    __builtin_memcpy(&u, &h, 2);
    return u;
}

static __device__ __forceinline__ int4 pack8(float4 a, float4 b) {
    union { unsigned short s[8]; int4 i; } r;
    r.s[0] = f2bf(a.x); r.s[1] = f2bf(a.y); r.s[2] = f2bf(a.z); r.s[3] = f2bf(a.w);
    r.s[4] = f2bf(b.x); r.s[5] = f2bf(b.y); r.s[6] = f2bf(b.z); r.s[7] = f2bf(b.w);
    return r.i;
}

// C[M][N] = A[M][256] * W[N][256]^T (+bias)*scale.  Tile 128x128, 4 waves,
// each wave 64x64 as 4x4 frags of 16x16x32 bf16 MFMA. (verified round 2)
template<bool A_BF16, bool OUT_F32>
__global__ __launch_bounds__(256) void proj_gemm(
    const void* __restrict__ Ap, const float* __restrict__ W,
    const float* __restrict__ bias, void* __restrict__ Outp, float scale)
{
    __shared__ alignas(16) unsigned short As[128][40];
    __shared__ alignas(16) unsigned short Bs[128][40];

    const int tid  = threadIdx.x;
    const int lane = tid & 63;
    const int wv   = tid >> 6;
    const int wm   = (wv >> 1) * 64, wn = (wv & 1) * 64;
    const int lr   = lane & 15, lg = lane >> 4;
    const int m0   = blockIdx.x * 128;
    const int n0   = blockIdx.y * 128;

    const int srow = tid >> 1;
    const int skc  = (tid & 1) * 16;

    f32x4 acc[4][4] = {};

    for (int k0 = 0; k0 < 256; k0 += 32) {
        __syncthreads();
        if (A_BF16) {
            const unsigned short* a = (const unsigned short*)Ap + (size_t)(m0 + srow) * 256 + k0 + skc;
            int4 v0 = *(const int4*)a;
            int4 v1 = *(const int4*)(a + 8);
            *(int4*)&As[srow][skc]     = v0;
            *(int4*)&As[srow][skc + 8] = v1;
        } else {
            const float* a = (const float*)Ap + (size_t)(m0 + srow) * 256 + k0 + skc;
            const float4* a4 = (const float4*)a;
            *(int4*)&As[srow][skc]     = pack8(a4[0], a4[1]);
            *(int4*)&As[srow][skc + 8] = pack8(a4[2], a4[3]);
        }
        {
            const float* b = W + (size_t)(n0 + srow) * 256 + k0 + skc;
            const float4* b4 = (const float4*)b;
            *(int4*)&Bs[srow][skc]     = pack8(b4[0], b4[1]);
            *(int4*)&Bs[srow][skc + 8] = pack8(b4[2], b4[3]);
        }
        __syncthreads();

        short8 af[4], bfr[4];
        #pragma unroll
        for (int fm = 0; fm < 4; ++fm)
            af[fm] = *(const short8*)&As[wm + fm * 16 + lr][lg * 8];
        #pragma unroll
        for (int fn = 0; fn < 4; ++fn)
            bfr[fn] = *(const short8*)&Bs[wn + fn * 16 + lr][lg * 8];
        #pragma unroll
        for (int fm = 0; fm < 4; ++fm)
            #pragma unroll
            for (int fn = 0; fn < 4; ++fn)
                acc[fm][fn] = __builtin_amdgcn_mfma_f32_16x16x32_bf16(
                    af[fm], bfr[fn], acc[fm][fn], 0, 0, 0);
    }

    float bvals[4];
    #pragma unroll
    for (int fn = 0; fn < 4; ++fn) bvals[fn] = bias[n0 + wn + fn * 16 + lr];

    #pragma unroll
    for (int fm = 0; fm < 4; ++fm) {
        #pragma unroll
        for (int fn = 0; fn < 4; ++fn) {
            #pragma unroll
            for (int r = 0; r < 4; ++r) {
                const int row = m0 + wm + fm * 16 + lg * 4 + r;
                const int col = n0 + wn + fn * 16 + lr;
                float val = (acc[fm][fn][r] + bvals[fn]) * scale;
                if (OUT_F32) ((float*)Outp)[(size_t)row * 256 + col] = val;
                else ((unsigned short*)Outp)[(size_t)row * 256 + col] = f2bf(val);
            }
        }
    }
}

// Flash attention, round 3.
// - V staged via coalesced b32 global loads into octet-subtiled LDS
//   Vs[oct][d][8] (kv octets): b128 writes AND b128 PV B-frag reads are
//   bank-conflict-free (no scalar transpose writes).
// - d-sliced PV: wave wv owns d-cols [wv*64, wv*64+64) for ALL 64 q rows;
//   softmax wave wv owns q-tile wv. P crosses waves via Ps (+barrier).
// - defer-rescale (THR=8): skip O-rescale pass when running max stable.
__global__ __launch_bounds__(256) void attn_kernel(
    const unsigned short* __restrict__ Q, const unsigned short* __restrict__ K,
    const unsigned short* __restrict__ V, unsigned short* __restrict__ A)
{
    __shared__ alignas(16) unsigned short Ks[32][264];      // [kv][d], pad +8
    __shared__ alignas(16) unsigned short Vs[4][256][8];    // [kv oct][d][kv&7]
    __shared__ alignas(16) unsigned short Ps[4][16][40];    // [qt][q][kv], pad +8
    __shared__ alignas(16) float Cor[4][16];                // rescale factors
    __shared__ alignas(16) float Ls[4][16];                 // final l per q row
    __shared__ int Flg[4];                                  // per-qt rescale flag

    const int tid  = threadIdx.x;
    const int lane = tid & 63;
    const int wv   = tid >> 6;
    const int lr   = lane & 15, lg = lane >> 4;
    const int b    = blockIdx.y;
    const size_t qblk = (size_t)b * SEQ + blockIdx.x * 64;  // block's first q row

    // Q frags: wave wv does softmax/QK for q-tile wv (rows qblk+wv*16 ..)
    short8 aq[8];
    #pragma unroll
    for (int c = 0; c < 8; ++c)
        aq[c] = *(const short8*)&Q[(qblk + wv * 16 + lr) * 256 + c * 32 + lg * 8];

    float m_run[4], l_run[4];
    f32x4 o[4][4] = {};   // [qt][dt]: rows qt*16+lg*4+r, cols wv*64+dt*16+lr
    #pragma unroll
    for (int r = 0; r < 4; ++r) { m_run[r] = -1e30f; l_run[r] = 0.f; }

    const int krow = tid >> 3, kcol = (tid & 7) * 32;   // K staging map
    const int dp = tid & 127, kh = tid >> 7;            // V staging map

    for (int it = 0; it < SEQ / 32; ++it) {
        const size_t kv0 = (size_t)b * SEQ + (size_t)it * 32;
        __syncthreads();   // prev iter's PV reads done before overwrite
        {   // stage K tile [32][256] row-major (b128)
            const int4* src = (const int4*)&K[(kv0 + krow) * 256 + kcol];
            int4 x0 = src[0], x1 = src[1], x2 = src[2], x3 = src[3];
            *(int4*)&Ks[krow][kcol]      = x0;
            *(int4*)&Ks[krow][kcol + 8]  = x1;
            *(int4*)&Ks[krow][kcol + 16] = x2;
            *(int4*)&Ks[krow][kcol + 24] = x3;
        }
        {   // stage V: thread owns cols {2dp,2dp+1} x kv rows kh*16..kh*16+15
            unsigned int y[16];
            #pragma unroll
            for (int r = 0; r < 16; ++r)
                y[r] = *(const unsigned int*)&V[(kv0 + kh * 16 + r) * 256 + 2 * dp];
            // octet u32s: even col from lo16s, odd col from hi16s
            #pragma unroll
            for (int h = 0; h < 2; ++h) {       // h: octet within our kv half
                int4 we, wo;
                unsigned int* pe = (unsigned int*)&we;
                unsigned int* po = (unsigned int*)&wo;
                #pragma unroll
                for (int j = 0; j < 4; ++j) {
                    unsigned int y0 = y[h * 8 + 2 * j], y1 = y[h * 8 + 2 * j + 1];
                    pe[j] = (y0 & 0xFFFFu) | (y1 << 16);
                    po[j] = (y0 >> 16) | (y1 & 0xFFFF0000u);
                }
                *(int4*)&Vs[2 * kh + h][2 * dp][0]     = we;
                *(int4*)&Vs[2 * kh + h][2 * dp + 1][0] = wo;
            }
        }
        __syncthreads();   // tiles ready

        // QK^T for own q-tile: two 16-col kv tiles, K=256 in 8 chunks
        f32x4 s0 = {}, s1 = {};
        #pragma unroll
        for (int c = 0; c < 8; ++c) {
            short8 kb0 = *(const short8*)&Ks[lr][c * 32 + lg * 8];
            short8 kb1 = *(const short8*)&Ks[16 + lr][c * 32 + lg * 8];
            s0 = __builtin_amdgcn_mfma_f32_16x16x32_bf16(aq[c], kb0, s0, 0, 0, 0);
            s1 = __builtin_amdgcn_mfma_f32_16x16x32_bf16(aq[c], kb1, s1, 0, 0, 0);
        }

        // online softmax (rows lg*4+r), defer-rescale THR=8
        float mx[4];
        bool needb = false;
        #pragma unroll
        for (int r = 0; r < 4; ++r) {
            float m2 = fmaxf(s0[r], s1[r]);
            #pragma unroll
            for (int sh = 1; sh < 16; sh <<= 1) m2 = fmaxf(m2, __shfl_xor(m2, sh, 64));
            mx[r] = m2;
            needb |= (m2 > m_run[r] + 8.f);
        }
        const int need = __any(needb);
        float corr[4];
        if (need) {
            #pragma unroll
            for (int r = 0; r < 4; ++r) {
                float mnew = fmaxf(m_run[r], mx[r]);
                corr[r] = __expf(m_run[r] - mnew);
                m_run[r] = mnew;
            }
            if (lr == 0) {
                #pragma unroll
                for (int r = 0; r < 4; ++r) Cor[wv][lg * 4 + r] = corr[r];
            }
        }
        if (lane == 0) Flg[wv] = need;
        #pragma unroll
        for (int r = 0; r < 4; ++r) {
            float p0 = __expf(s0[r] - m_run[r]);
            float p1 = __expf(s1[r] - m_run[r]);
            float rs = p0 + p1;
            #pragma unroll
            for (int sh = 1; sh < 16; sh <<= 1) rs += __shfl_xor(rs, sh, 64);
            l_run[r] = (need ? l_run[r] * corr[r] : l_run[r]) + rs;
            Ps[wv][lg * 4 + r][lr]      = f2bf(p0);
            Ps[wv][lg * 4 + r][16 + lr] = f2bf(p1);
        }
        __syncthreads();   // P/Cor/Flg ready

        // PV for own d-slice, all 4 q-tiles
        short8 pa[4];
        #pragma unroll
        for (int qt = 0; qt < 4; ++qt)
            pa[qt] = *(const short8*)&Ps[qt][lr][lg * 8];
        #pragma unroll
        for (int qt = 0; qt < 4; ++qt) {
            if (Flg[qt]) {
                float4 c4 = *(const float4*)&Cor[qt][lg * 4];
                #pragma unroll
                for (int dt = 0; dt < 4; ++dt) {
                    o[qt][dt][0] *= c4.x; o[qt][dt][1] *= c4.y;
                    o[qt][dt][2] *= c4.z; o[qt][dt][3] *= c4.w;
                }
            }
            #pragma unroll
            for (int dt = 0; dt < 4; ++dt) {
                short8 vb = *(const short8*)&Vs[lg][wv * 64 + dt * 16 + lr][0];
                o[qt][dt] = __builtin_amdgcn_mfma_f32_16x16x32_bf16(pa[qt], vb, o[qt][dt], 0, 0, 0);
            }
        }
    }

    // broadcast l, normalize, write
    if (lr == 0) {
        #pragma unroll
        for (int r = 0; r < 4; ++r) Ls[wv][lg * 4 + r] = l_run[r];
    }
    __syncthreads();
    #pragma unroll
    for (int qt = 0; qt < 4; ++qt) {
        float4 l4 = *(const float4*)&Ls[qt][lg * 4];
        float inv[4] = {1.f / l4.x, 1.f / l4.y, 1.f / l4.z, 1.f / l4.w};
        #pragma unroll
        for (int dt = 0; dt < 4; ++dt)
            #pragma unroll
            for (int r = 0; r < 4; ++r)
                A[(qblk + qt * 16 + lg * 4 + r) * 256 + wv * 64 + dt * 16 + lr] =
                    f2bf(o[qt][dt][r] * inv[r]);
    }
}

extern "C" void kernel_launch(void* const* d_in, const int* in_sizes, int n_in,
                              void* d_out, int out_size, void* d_ws, size_t ws_size,
                              hipStream_t stream) {
    (void)in_sizes; (void)n_in; (void)out_size; (void)ws_size;
    const float* x  = (const float*)d_in[0];
    const float* Wq = (const float*)d_in[1];
    const float* bq = (const float*)d_in[2];
    const float* Wk = (const float*)d_in[3];
    const float* bk = (const float*)d_in[4];
    const float* Wv = (const float*)d_in[5];
    const float* bv = (const float*)d_in[6];
    const float* Wo = (const float*)d_in[7];
    const float* bo = (const float*)d_in[8];
    float* out = (float*)d_out;

    char* ws = (char*)d_ws;
    const size_t MB16 = (size_t)16 * 1024 * 1024;
    unsigned short* qb = (unsigned short*)(ws);
    unsigned short* kb = (unsigned short*)(ws + MB16);
    unsigned short* vb = (unsigned short*)(ws + 2 * MB16);
    unsigned short* ab = (unsigned short*)(ws + 3 * MB16);

    dim3 gg(256, 2), bb(256);
    proj_gemm<false, false><<<gg, bb, 0, stream>>>(x, Wq, bq, qb, 0.0625f);
    proj_gemm<false, false><<<gg, bb, 0, stream>>>(x, Wk, bk, kb, 1.0f);
    proj_gemm<false, false><<<gg, bb, 0, stream>>>(x, Wv, bv, vb, 1.0f);
    attn_kernel<<<dim3(128, NBATCH), bb, 0, stream>>>(qb, kb, vb, ab);
    proj_gemm<true, true><<<gg, bb, 0, stream>>>(ab, Wo, bo, out, 1.0f);
}

// Round 5
// 594.645 us; speedup vs baseline: 1.4472x; 1.2529x over previous
//
#include <hip/hip_runtime.h>
#include <hip/hip_bf16.h>

typedef __attribute__((ext_vector_type(8))) short short8;
typedef __attribute__((ext_vector_type(4))) float f32x4;

#define SEQ 8192
#define NBATCH 4

static __device__ __forceinline__ unsigned short f2bf(float f) {
    __hip_bfloat16 h = __float2bfloat16(f);
    unsigned short u;
    __builtin_memcpy(&u, &h, 2);
    return u;
}

static __device__ __forceinline__ int4 pack8(float4 a, float4 b) {
    union { unsigned short s[8]; int4 i; } r;
    r.s[0] = f2bf(a.x); r.s[1] = f2bf(a.y); r.s[2] = f2bf(a.z); r.s[3] = f2bf(a.w);
    r.s[4] = f2bf(b.x); r.s[5] = f2bf(b.y); r.s[6] = f2bf(b.z); r.s[7] = f2bf(b.w);
    return r.i;
}

// C[M][N] = A[M][256] * W[N][256]^T (+bias)*scale.  Tile 128x128, 4 waves,
// each wave 64x64 as 4x4 frags of 16x16x32 bf16 MFMA. (verified round 2)
template<bool A_BF16, bool OUT_F32>
__global__ __launch_bounds__(256) void proj_gemm(
    const void* __restrict__ Ap, const float* __restrict__ W,
    const float* __restrict__ bias, void* __restrict__ Outp, float scale)
{
    __shared__ alignas(16) unsigned short As[128][40];
    __shared__ alignas(16) unsigned short Bs[128][40];

    const int tid  = threadIdx.x;
    const int lane = tid & 63;
    const int wv   = tid >> 6;
    const int wm   = (wv >> 1) * 64, wn = (wv & 1) * 64;
    const int lr   = lane & 15, lg = lane >> 4;
    const int m0   = blockIdx.x * 128;
    const int n0   = blockIdx.y * 128;

    const int srow = tid >> 1;
    const int skc  = (tid & 1) * 16;

    f32x4 acc[4][4] = {};

    for (int k0 = 0; k0 < 256; k0 += 32) {
        __syncthreads();
        if (A_BF16) {
            const unsigned short* a = (const unsigned short*)Ap + (size_t)(m0 + srow) * 256 + k0 + skc;
            int4 v0 = *(const int4*)a;
            int4 v1 = *(const int4*)(a + 8);
            *(int4*)&As[srow][skc]     = v0;
            *(int4*)&As[srow][skc + 8] = v1;
        } else {
            const float* a = (const float*)Ap + (size_t)(m0 + srow) * 256 + k0 + skc;
            const float4* a4 = (const float4*)a;
            *(int4*)&As[srow][skc]     = pack8(a4[0], a4[1]);
            *(int4*)&As[srow][skc + 8] = pack8(a4[2], a4[3]);
        }
        {
            const float* b = W + (size_t)(n0 + srow) * 256 + k0 + skc;
            const float4* b4 = (const float4*)b;
            *(int4*)&Bs[srow][skc]     = pack8(b4[0], b4[1]);
            *(int4*)&Bs[srow][skc + 8] = pack8(b4[2], b4[3]);
        }
        __syncthreads();

        short8 af[4], bfr[4];
        #pragma unroll
        for (int fm = 0; fm < 4; ++fm)
            af[fm] = *(const short8*)&As[wm + fm * 16 + lr][lg * 8];
        #pragma unroll
        for (int fn = 0; fn < 4; ++fn)
            bfr[fn] = *(const short8*)&Bs[wn + fn * 16 + lr][lg * 8];
        #pragma unroll
        for (int fm = 0; fm < 4; ++fm)
            #pragma unroll
            for (int fn = 0; fn < 4; ++fn)
                acc[fm][fn] = __builtin_amdgcn_mfma_f32_16x16x32_bf16(
                    af[fm], bfr[fn], acc[fm][fn], 0, 0, 0);
    }

    float bvals[4];
    #pragma unroll
    for (int fn = 0; fn < 4; ++fn) bvals[fn] = bias[n0 + wn + fn * 16 + lr];

    #pragma unroll
    for (int fm = 0; fm < 4; ++fm) {
        #pragma unroll
        for (int fn = 0; fn < 4; ++fn) {
            #pragma unroll
            for (int r = 0; r < 4; ++r) {
                const int row = m0 + wm + fm * 16 + lg * 4 + r;
                const int col = n0 + wn + fn * 16 + lr;
                float val = (acc[fm][fn][r] + bvals[fn]) * scale;
                if (OUT_F32) ((float*)Outp)[(size_t)row * 256 + col] = val;
                else ((unsigned short*)Outp)[(size_t)row * 256 + col] = f2bf(val);
            }
        }
    }
}

// Flash attention, round 5.
// - SWAPPED QK: mfma(K,Q) -> D[kv][q]; lane (lr,lg) holds 8 kv-scores for
//   q=lr. Softmax: in-register 8-way reduce + 2 shfl_xor (was 32 shfls);
//   m/l are per-lane scalars.
// - P is kv-contiguous per lane -> packed bf16, 2x ds_write_b64 into Ps
//   (was 8 conflicted scalar u16 writes). pa b128 reads unchanged.
// - Vs slot XOR-swizzle (d ^ ((d>>3)&1)): staging writes at conflict floor.
// - vb reads hoisted out of qt loop (4 reads).
// - d-sliced PV + defer-rescale (THR=8) kept from round 4.
#define VSLOT(d) ((d) ^ (((d) >> 3) & 1))

__global__ __launch_bounds__(256) void attn_kernel(
    const unsigned short* __restrict__ Q, const unsigned short* __restrict__ K,
    const unsigned short* __restrict__ V, unsigned short* __restrict__ A)
{
    __shared__ alignas(16) unsigned short Ks[32][264];      // [kv][d], pad +8
    __shared__ alignas(16) unsigned short Vs[4][256][8];    // [kv oct][d slot][kv&7]
    __shared__ alignas(16) unsigned short Ps[4][16][40];    // [qt][q][kv], pad
    __shared__ alignas(16) float Cor[4][16];                // rescale factors
    __shared__ alignas(16) float Ls[4][16];                 // final l per q row
    __shared__ int Flg[4];                                  // per-qt rescale flag

    const int tid  = threadIdx.x;
    const int lane = tid & 63;
    const int wv   = tid >> 6;
    const int lr   = lane & 15, lg = lane >> 4;
    const int b    = blockIdx.y;
    const size_t qblk = (size_t)b * SEQ + blockIdx.x * 64;  // block's first q row

    // Q frags (B-operand now): wave wv owns q-tile wv
    short8 aq[8];
    #pragma unroll
    for (int c = 0; c < 8; ++c)
        aq[c] = *(const short8*)&Q[(qblk + wv * 16 + lr) * 256 + c * 32 + lg * 8];

    float m_run = -1e30f, l_run = 0.f;   // per-lane: q-row = lr
    f32x4 o[4][4] = {};   // [qt][dt]: rows qt*16+lg*4+r, cols wv*64+dt*16+lr

    const int krow = tid >> 3, kcol = (tid & 7) * 32;   // K staging map
    const int dp = tid & 127, kh = tid >> 7;            // V staging map

    for (int it = 0; it < SEQ / 32; ++it) {
        const size_t kv0 = (size_t)b * SEQ + (size_t)it * 32;
        __syncthreads();   // prev iter's PV reads done before overwrite
        {   // stage K tile [32][256] row-major (b128)
            const int4* src = (const int4*)&K[(kv0 + krow) * 256 + kcol];
            int4 x0 = src[0], x1 = src[1], x2 = src[2], x3 = src[3];
            *(int4*)&Ks[krow][kcol]      = x0;
            *(int4*)&Ks[krow][kcol + 8]  = x1;
            *(int4*)&Ks[krow][kcol + 16] = x2;
            *(int4*)&Ks[krow][kcol + 24] = x3;
        }
        {   // stage V: thread owns cols {2dp,2dp+1} x kv rows kh*16..kh*16+15
            unsigned int y[16];
            #pragma unroll
            for (int r = 0; r < 16; ++r)
                y[r] = *(const unsigned int*)&V[(kv0 + kh * 16 + r) * 256 + 2 * dp];
            #pragma unroll
            for (int h = 0; h < 2; ++h) {       // h: octet within our kv half
                int4 we, wo;
                unsigned int* pe = (unsigned int*)&we;
                unsigned int* po = (unsigned int*)&wo;
                #pragma unroll
                for (int j = 0; j < 4; ++j) {
                    unsigned int y0 = y[h * 8 + 2 * j], y1 = y[h * 8 + 2 * j + 1];
                    pe[j] = (y0 & 0xFFFFu) | (y1 << 16);
                    po[j] = (y0 >> 16) | (y1 & 0xFFFF0000u);
                }
                *(int4*)&Vs[2 * kh + h][VSLOT(2 * dp)][0]     = we;
                *(int4*)&Vs[2 * kh + h][VSLOT(2 * dp + 1)][0] = wo;
            }
        }
        __syncthreads();   // tiles ready

        // Swapped QK^T: D[kv][q].  s0 = kv rows 0..15, s1 = kv rows 16..31.
        f32x4 s0 = {}, s1 = {};
        #pragma unroll
        for (int c = 0; c < 8; ++c) {
            short8 kb0 = *(const short8*)&Ks[lr][c * 32 + lg * 8];
            short8 kb1 = *(const short8*)&Ks[16 + lr][c * 32 + lg * 8];
            s0 = __builtin_amdgcn_mfma_f32_16x16x32_bf16(kb0, aq[c], s0, 0, 0, 0);
            s1 = __builtin_amdgcn_mfma_f32_16x16x32_bf16(kb1, aq[c], s1, 0, 0, 0);
        }
        // lane (lr,lg): s0[r] = S[kv=4lg+r][q=lr], s1[r] = S[kv=16+4lg+r][q=lr]

        // online softmax for q=lr: in-reg 8-way max + 2 shfl (lg axis)
        float mx = fmaxf(fmaxf(fmaxf(s0[0], s0[1]), fmaxf(s0[2], s0[3])),
                         fmaxf(fmaxf(s1[0], s1[1]), fmaxf(s1[2], s1[3])));
        mx = fmaxf(mx, __shfl_xor(mx, 16, 64));
        mx = fmaxf(mx, __shfl_xor(mx, 32, 64));

        const int need = __any(mx > m_run + 8.f);
        float corr = 1.f;
        if (need) {
            float mnew = fmaxf(m_run, mx);
            corr = __expf(m_run - mnew);
            m_run = mnew;
            if (lane < 16) Cor[wv][lr] = corr;
        }
        if (lane == 0) Flg[wv] = need;

        float p0[4], p1[4];
        #pragma unroll
        for (int r = 0; r < 4; ++r) {
            p0[r] = __expf(s0[r] - m_run);
            p1[r] = __expf(s1[r] - m_run);
        }
        float rs = ((p0[0] + p0[1]) + (p0[2] + p0[3])) +
                   ((p1[0] + p1[1]) + (p1[2] + p1[3]));
        rs += __shfl_xor(rs, 16, 64);
        rs += __shfl_xor(rs, 32, 64);
        l_run = (need ? l_run * corr : l_run) + rs;

        // pack P (kv-contiguous per lane) -> 2x b64 writes
        {
            unsigned int w0 = (unsigned)f2bf(p0[0]) | ((unsigned)f2bf(p0[1]) << 16);
            unsigned int w1 = (unsigned)f2bf(p0[2]) | ((unsigned)f2bf(p0[3]) << 16);
            unsigned int w2 = (unsigned)f2bf(p1[0]) | ((unsigned)f2bf(p1[1]) << 16);
            unsigned int w3 = (unsigned)f2bf(p1[2]) | ((unsigned)f2bf(p1[3]) << 16);
            *(unsigned long long*)&Ps[wv][lr][4 * lg] =
                (unsigned long long)w0 | ((unsigned long long)w1 << 32);
            *(unsigned long long*)&Ps[wv][lr][16 + 4 * lg] =
                (unsigned long long)w2 | ((unsigned long long)w3 << 32);
        }
        __syncthreads();   // P/Cor/Flg ready

        // PV for own d-slice, all 4 q-tiles
        short8 pa[4];
        #pragma unroll
        for (int qt = 0; qt < 4; ++qt)
            pa[qt] = *(const short8*)&Ps[qt][lr][lg * 8];
        short8 vbr[4];
        #pragma unroll
        for (int dt = 0; dt < 4; ++dt)
            vbr[dt] = *(const short8*)&Vs[lg][VSLOT(wv * 64 + dt * 16 + lr)][0];
        #pragma unroll
        for (int qt = 0; qt < 4; ++qt) {
            if (Flg[qt]) {
                float4 c4 = *(const float4*)&Cor[qt][lg * 4];
                #pragma unroll
                for (int dt = 0; dt < 4; ++dt) {
                    o[qt][dt][0] *= c4.x; o[qt][dt][1] *= c4.y;
                    o[qt][dt][2] *= c4.z; o[qt][dt][3] *= c4.w;
                }
            }
            #pragma unroll
            for (int dt = 0; dt < 4; ++dt)
                o[qt][dt] = __builtin_amdgcn_mfma_f32_16x16x32_bf16(pa[qt], vbr[dt], o[qt][dt], 0, 0, 0);
        }
    }

    // broadcast l, normalize, write
    if (lane < 16) Ls[wv][lr] = l_run;
    __syncthreads();
    #pragma unroll
    for (int qt = 0; qt < 4; ++qt) {
        float4 l4 = *(const float4*)&Ls[qt][lg * 4];
        float inv[4] = {1.f / l4.x, 1.f / l4.y, 1.f / l4.z, 1.f / l4.w};
        #pragma unroll
        for (int dt = 0; dt < 4; ++dt)
            #pragma unroll
            for (int r = 0; r < 4; ++r)
                A[(qblk + qt * 16 + lg * 4 + r) * 256 + wv * 64 + dt * 16 + lr] =
                    f2bf(o[qt][dt][r] * inv[r]);
    }
}

extern "C" void kernel_launch(void* const* d_in, const int* in_sizes, int n_in,
                              void* d_out, int out_size, void* d_ws, size_t ws_size,
                              hipStream_t stream) {
    (void)in_sizes; (void)n_in; (void)out_size; (void)ws_size;
    const float* x  = (const float*)d_in[0];
    const float* Wq = (const float*)d_in[1];
    const float* bq = (const float*)d_in[2];
    const float* Wk = (const float*)d_in[3];
    const float* bk = (const float*)d_in[4];
    const float* Wv = (const float*)d_in[5];
    const float* bv = (const float*)d_in[6];
    const float* Wo = (const float*)d_in[7];
    const float* bo = (const float*)d_in[8];
    float* out = (float*)d_out;

    char* ws = (char*)d_ws;
    const size_t MB16 = (size_t)16 * 1024 * 1024;
    unsigned short* qb = (unsigned short*)(ws);
    unsigned short* kb = (unsigned short*)(ws + MB16);
    unsigned short* vb = (unsigned short*)(ws + 2 * MB16);
    unsigned short* ab = (unsigned short*)(ws + 3 * MB16);

    dim3 gg(256, 2), bb(256);
    proj_gemm<false, false><<<gg, bb, 0, stream>>>(x, Wq, bq, qb, 0.0625f);
    proj_gemm<false, false><<<gg, bb, 0, stream>>>(x, Wk, bk, kb, 1.0f);
    proj_gemm<false, false><<<gg, bb, 0, stream>>>(x, Wv, bv, vb, 1.0f);
    attn_kernel<<<dim3(128, NBATCH), bb, 0, stream>>>(qb, kb, vb, ab);
    proj_gemm<true, true><<<gg, bb, 0, stream>>>(ab, Wo, bo, out, 1.0f);
}

// Round 6
// 503.914 us; speedup vs baseline: 1.7077x; 1.1801x over previous
//
#include <hip/hip_runtime.h>
#include <hip/hip_bf16.h>

typedef __attribute__((ext_vector_type(8))) short short8;
typedef __attribute__((ext_vector_type(4))) float f32x4;

#define SEQ 8192
#define NBATCH 4
#define NT (SEQ / 32)

static __device__ __forceinline__ unsigned short f2bf(float f) {
    __hip_bfloat16 h = __float2bfloat16(f);
    unsigned short u;
    __builtin_memcpy(&u, &h, 2);
    return u;
}

static __device__ __forceinline__ int4 pack8(float4 a, float4 b) {
    union { unsigned short s[8]; int4 i; } r;
    r.s[0] = f2bf(a.x); r.s[1] = f2bf(a.y); r.s[2] = f2bf(a.z); r.s[3] = f2bf(a.w);
    r.s[4] = f2bf(b.x); r.s[5] = f2bf(b.y); r.s[6] = f2bf(b.z); r.s[7] = f2bf(b.w);
    return r.i;
}

// C[M][N] = A[M][256] * W[N][256]^T (+bias)*scale.  Tile 128x128, 4 waves.
// OMODE: 0 = bf16 row-major, 1 = f32 row-major, 2 = bf16 transposed per batch
// (out[(b*256+col)*8192 + s], for V^T). (structure verified rounds 2-5)
template<bool A_BF16, int OMODE>
__global__ __launch_bounds__(256) void proj_gemm(
    const void* __restrict__ Ap, const float* __restrict__ W,
    const float* __restrict__ bias, void* __restrict__ Outp, float scale)
{
    __shared__ alignas(16) unsigned short As[128][40];
    __shared__ alignas(16) unsigned short Bs[128][40];

    const int tid  = threadIdx.x;
    const int lane = tid & 63;
    const int wv   = tid >> 6;
    const int wm   = (wv >> 1) * 64, wn = (wv & 1) * 64;
    const int lr   = lane & 15, lg = lane >> 4;
    const int m0   = blockIdx.x * 128;
    const int n0   = blockIdx.y * 128;

    const int srow = tid >> 1;
    const int skc  = (tid & 1) * 16;

    f32x4 acc[4][4] = {};

    for (int k0 = 0; k0 < 256; k0 += 32) {
        __syncthreads();
        if (A_BF16) {
            const unsigned short* a = (const unsigned short*)Ap + (size_t)(m0 + srow) * 256 + k0 + skc;
            int4 v0 = *(const int4*)a;
            int4 v1 = *(const int4*)(a + 8);
            *(int4*)&As[srow][skc]     = v0;
            *(int4*)&As[srow][skc + 8] = v1;
        } else {
            const float* a = (const float*)Ap + (size_t)(m0 + srow) * 256 + k0 + skc;
            const float4* a4 = (const float4*)a;
            *(int4*)&As[srow][skc]     = pack8(a4[0], a4[1]);
            *(int4*)&As[srow][skc + 8] = pack8(a4[2], a4[3]);
        }
        {
            const float* b = W + (size_t)(n0 + srow) * 256 + k0 + skc;
            const float4* b4 = (const float4*)b;
            *(int4*)&Bs[srow][skc]     = pack8(b4[0], b4[1]);
            *(int4*)&Bs[srow][skc + 8] = pack8(b4[2], b4[3]);
        }
        __syncthreads();

        short8 af[4], bfr[4];
        #pragma unroll
        for (int fm = 0; fm < 4; ++fm)
            af[fm] = *(const short8*)&As[wm + fm * 16 + lr][lg * 8];
        #pragma unroll
        for (int fn = 0; fn < 4; ++fn)
            bfr[fn] = *(const short8*)&Bs[wn + fn * 16 + lr][lg * 8];
        #pragma unroll
        for (int fm = 0; fm < 4; ++fm)
            #pragma unroll
            for (int fn = 0; fn < 4; ++fn)
                acc[fm][fn] = __builtin_amdgcn_mfma_f32_16x16x32_bf16(
                    af[fm], bfr[fn], acc[fm][fn], 0, 0, 0);
    }

    float bvals[4];
    #pragma unroll
    for (int fn = 0; fn < 4; ++fn) bvals[fn] = bias[n0 + wn + fn * 16 + lr];

    #pragma unroll
    for (int fm = 0; fm < 4; ++fm) {
        #pragma unroll
        for (int fn = 0; fn < 4; ++fn) {
            #pragma unroll
            for (int r = 0; r < 4; ++r) {
                const int row = m0 + wm + fm * 16 + lg * 4 + r;
                const int col = n0 + wn + fn * 16 + lr;
                float val = (acc[fm][fn][r] + bvals[fn]) * scale;
                if (OMODE == 1) {
                    ((float*)Outp)[(size_t)row * 256 + col] = val;
                } else if (OMODE == 0) {
                    ((unsigned short*)Outp)[(size_t)row * 256 + col] = f2bf(val);
                } else {  // V^T: [b][d=col][s]
                    const int bb = row >> 13, s = row & 8191;
                    ((unsigned short*)Outp)[((size_t)(bb * 256 + col) << 13) + s] = f2bf(val);
                }
            }
        }
    }
}

// Flash attention, round 6.
// - Scores pre-scaled to log2 domain (Q scale folds 1/sqrt(d)*log2e) -> exp2.
// - Swapped QK (D[kv][q]), per-lane softmax for q=lr, P via 2x ds_write_b64.
// - V^T in global [b][d][S]: PV B-frags loaded DIRECTLY from global (no V LDS).
// - Double-buffered Ks/Ps, software-pipelined PV (lags 1 iter): ONE barrier/iter.
// - d-sliced PV + defer-rescale (THR=11 log2-units).
__global__ __launch_bounds__(256) void attn_kernel(
    const unsigned short* __restrict__ Q, const unsigned short* __restrict__ K,
    const unsigned short* __restrict__ Vt, unsigned short* __restrict__ A)
{
    __shared__ alignas(16) unsigned short Ks[2][32][264];   // [buf][kv][d], pad +8
    __shared__ alignas(16) unsigned short Ps[2][4][16][40]; // [buf][qt][q][kv], pad
    __shared__ alignas(16) float Cor[2][4][16];
    __shared__ alignas(16) float Ls[4][16];
    __shared__ int Flg[2][4];

    const int tid  = threadIdx.x;
    const int lane = tid & 63;
    const int wv   = tid >> 6;
    const int lr   = lane & 15, lg = lane >> 4;
    const int b    = blockIdx.y;
    const size_t qblk = (size_t)b * SEQ + blockIdx.x * 64;

    // Q frags (B-operand): wave wv owns q-tile wv
    short8 aq[8];
    #pragma unroll
    for (int c = 0; c < 8; ++c)
        aq[c] = *(const short8*)&Q[(qblk + wv * 16 + lr) * 256 + c * 32 + lg * 8];

    float m_run = -1e30f, l_run = 0.f;   // per-lane: q-row = lr (log2 domain)
    f32x4 o[4][4] = {};   // [qt][dt]: rows qt*16+lg*4+r, cols wv*64+dt*16+lr

    const int krow = tid >> 3, kcol = (tid & 7) * 32;   // K staging map
    const unsigned short* Vb = Vt + ((size_t)b * 256 << 13);
    size_t vrow[4];       // per-lane V^T row byte offsets (elements)
    #pragma unroll
    for (int dt = 0; dt < 4; ++dt)
        vrow[dt] = (size_t)(wv * 64 + dt * 16 + lr) << 13;

    // prologue: stage tile 0 into Ks[0]
    {
        const int4* src = (const int4*)&K[((size_t)b * SEQ + krow) * 256 + kcol];
        int4 x0 = src[0], x1 = src[1], x2 = src[2], x3 = src[3];
        *(int4*)&Ks[0][krow][kcol]      = x0;
        *(int4*)&Ks[0][krow][kcol + 8]  = x1;
        *(int4*)&Ks[0][krow][kcol + 16] = x2;
        *(int4*)&Ks[0][krow][kcol + 24] = x3;
    }
    __syncthreads();

    for (int it = 0; it < NT; ++it) {
        const int p = it & 1;
        // issue next K-tile loads early (latency hides under QK)
        int4 x0, x1, x2, x3;
        const bool have = (it + 1 < NT);
        if (have) {
            const int4* src = (const int4*)&K[((size_t)b * SEQ + (it + 1) * 32 + krow) * 256 + kcol];
            x0 = src[0]; x1 = src[1]; x2 = src[2]; x3 = src[3];
        }
        // V^T frags for PV(it-1), direct from global (L2-resident)
        short8 vbr[4];
        if (it > 0) {
            const size_t kvp = (size_t)(it - 1) * 32 + lg * 8;
            #pragma unroll
            for (int dt = 0; dt < 4; ++dt)
                vbr[dt] = *(const short8*)&Vb[vrow[dt] + kvp];
        }

        // QK^T from Ks[p] (swapped): s0 = kv 0..15, s1 = kv 16..31
        f32x4 s0 = {}, s1 = {};
        #pragma unroll
        for (int c = 0; c < 8; ++c) {
            short8 kb0 = *(const short8*)&Ks[p][lr][c * 32 + lg * 8];
            short8 kb1 = *(const short8*)&Ks[p][16 + lr][c * 32 + lg * 8];
            s0 = __builtin_amdgcn_mfma_f32_16x16x32_bf16(kb0, aq[c], s0, 0, 0, 0);
            s1 = __builtin_amdgcn_mfma_f32_16x16x32_bf16(kb1, aq[c], s1, 0, 0, 0);
        }

        // write next K tile into the other buffer
        if (have) {
            *(int4*)&Ks[p ^ 1][krow][kcol]      = x0;
            *(int4*)&Ks[p ^ 1][krow][kcol + 8]  = x1;
            *(int4*)&Ks[p ^ 1][krow][kcol + 16] = x2;
            *(int4*)&Ks[p ^ 1][krow][kcol + 24] = x3;
        }

        // online softmax for q=lr (log2 domain), defer-rescale THR=11
        float mx = fmaxf(fmaxf(fmaxf(s0[0], s0[1]), fmaxf(s0[2], s0[3])),
                         fmaxf(fmaxf(s1[0], s1[1]), fmaxf(s1[2], s1[3])));
        mx = fmaxf(mx, __shfl_xor(mx, 16, 64));
        mx = fmaxf(mx, __shfl_xor(mx, 32, 64));

        const int need = __any(mx > m_run + 11.0f);
        float corr = 1.f;
        if (need) {
            float mnew = fmaxf(m_run, mx);
            corr = exp2f(m_run - mnew);
            m_run = mnew;
            if (lane < 16) Cor[p ^ 1][wv][lr] = corr;
        }
        if (lane == 0) Flg[p ^ 1][wv] = need;

        float p0[4], p1[4];
        #pragma unroll
        for (int r = 0; r < 4; ++r) {
            p0[r] = exp2f(s0[r] - m_run);
            p1[r] = exp2f(s1[r] - m_run);
        }
        float rs = ((p0[0] + p0[1]) + (p0[2] + p0[3])) +
                   ((p1[0] + p1[1]) + (p1[2] + p1[3]));
        rs += __shfl_xor(rs, 16, 64);
        rs += __shfl_xor(rs, 32, 64);
        l_run = (need ? l_run * corr : l_run) + rs;

        {   // pack P -> Ps[p^1] (kv-contiguous per lane), 2x b64
            unsigned int w0 = (unsigned)f2bf(p0[0]) | ((unsigned)f2bf(p0[1]) << 16);
            unsigned int w1 = (unsigned)f2bf(p0[2]) | ((unsigned)f2bf(p0[3]) << 16);
            unsigned int w2 = (unsigned)f2bf(p1[0]) | ((unsigned)f2bf(p1[1]) << 16);
            unsigned int w3 = (unsigned)f2bf(p1[2]) | ((unsigned)f2bf(p1[3]) << 16);
            *(unsigned long long*)&Ps[p ^ 1][wv][lr][4 * lg] =
                (unsigned long long)w0 | ((unsigned long long)w1 << 32);
            *(unsigned long long*)&Ps[p ^ 1][wv][lr][16 + 4 * lg] =
                (unsigned long long)w2 | ((unsigned long long)w3 << 32);
        }

        // PV(it-1): P from Ps[p], rescale via Flg/Cor[p], V frags from global
        if (it > 0) {
            short8 pa[4];
            #pragma unroll
            for (int qt = 0; qt < 4; ++qt)
                pa[qt] = *(const short8*)&Ps[p][qt][lr][lg * 8];
            #pragma unroll
            for (int qt = 0; qt < 4; ++qt) {
                if (Flg[p][qt]) {
                    float4 c4 = *(const float4*)&Cor[p][qt][lg * 4];
                    #pragma unroll
                    for (int dt = 0; dt < 4; ++dt) {
                        o[qt][dt][0] *= c4.x; o[qt][dt][1] *= c4.y;
                        o[qt][dt][2] *= c4.z; o[qt][dt][3] *= c4.w;
                    }
                }
                #pragma unroll
                for (int dt = 0; dt < 4; ++dt)
                    o[qt][dt] = __builtin_amdgcn_mfma_f32_16x16x32_bf16(pa[qt], vbr[dt], o[qt][dt], 0, 0, 0);
            }
        }
        __syncthreads();   // Ks[p^1], Ps[p^1] ready; Ks[p]/Ps[p] reads done
    }

    // epilogue: PV for the last tile (P(NT-1) lives in buffer NT&1 = 0)
    {
        const int p = NT & 1;
        const size_t kvp = (size_t)(NT - 1) * 32 + lg * 8;
        short8 vbr[4];
        #pragma unroll
        for (int dt = 0; dt < 4; ++dt)
            vbr[dt] = *(const short8*)&Vb[vrow[dt] + kvp];
        short8 pa[4];
        #pragma unroll
        for (int qt = 0; qt < 4; ++qt)
            pa[qt] = *(const short8*)&Ps[p][qt][lr][lg * 8];
        #pragma unroll
        for (int qt = 0; qt < 4; ++qt) {
            if (Flg[p][qt]) {
                float4 c4 = *(const float4*)&Cor[p][qt][lg * 4];
                #pragma unroll
                for (int dt = 0; dt < 4; ++dt) {
                    o[qt][dt][0] *= c4.x; o[qt][dt][1] *= c4.y;
                    o[qt][dt][2] *= c4.z; o[qt][dt][3] *= c4.w;
                }
            }
            #pragma unroll
            for (int dt = 0; dt < 4; ++dt)
                o[qt][dt] = __builtin_amdgcn_mfma_f32_16x16x32_bf16(pa[qt], vbr[dt], o[qt][dt], 0, 0, 0);
        }
    }

    // broadcast l, normalize, write
    if (lane < 16) Ls[wv][lr] = l_run;
    __syncthreads();
    #pragma unroll
    for (int qt = 0; qt < 4; ++qt) {
        float4 l4 = *(const float4*)&Ls[qt][lg * 4];
        float inv[4] = {1.f / l4.x, 1.f / l4.y, 1.f / l4.z, 1.f / l4.w};
        #pragma unroll
        for (int dt = 0; dt < 4; ++dt)
            #pragma unroll
            for (int r = 0; r < 4; ++r)
                A[(qblk + qt * 16 + lg * 4 + r) * 256 + wv * 64 + dt * 16 + lr] =
                    f2bf(o[qt][dt][r] * inv[r]);
    }
}

extern "C" void kernel_launch(void* const* d_in, const int* in_sizes, int n_in,
                              void* d_out, int out_size, void* d_ws, size_t ws_size,
                              hipStream_t stream) {
    (void)in_sizes; (void)n_in; (void)out_size; (void)ws_size;
    const float* x  = (const float*)d_in[0];
    const float* Wq = (const float*)d_in[1];
    const float* bq = (const float*)d_in[2];
    const float* Wk = (const float*)d_in[3];
    const float* bk = (const float*)d_in[4];
    const float* Wv = (const float*)d_in[5];
    const float* bv = (const float*)d_in[6];
    const float* Wo = (const float*)d_in[7];
    const float* bo = (const float*)d_in[8];
    float* out = (float*)d_out;

    char* ws = (char*)d_ws;
    const size_t MB16 = (size_t)16 * 1024 * 1024;
    unsigned short* qb = (unsigned short*)(ws);
    unsigned short* kb = (unsigned short*)(ws + MB16);
    unsigned short* vt = (unsigned short*)(ws + 2 * MB16);  // V^T [b][d][S]
    unsigned short* ab = (unsigned short*)(ws + 3 * MB16);

    dim3 gg(256, 2), bb(256);
    // scores in log2 domain: Q scale = d^-0.5 * log2(e)
    proj_gemm<false, 0><<<gg, bb, 0, stream>>>(x, Wq, bq, qb, 0.0625f * 1.44269504f);
    proj_gemm<false, 0><<<gg, bb, 0, stream>>>(x, Wk, bk, kb, 1.0f);
    proj_gemm<false, 2><<<gg, bb, 0, stream>>>(x, Wv, bv, vt, 1.0f);
    attn_kernel<<<dim3(128, NBATCH), bb, 0, stream>>>(qb, kb, vt, ab);
    proj_gemm<true, 1><<<gg, bb, 0, stream>>>(ab, Wo, bo, out, 1.0f);
}